// Round 6
// baseline (403.972 us; speedup 1.0000x reference)
//
#include <hip/hip_runtime.h>

// Physics_Attention_Irregular_Mesh — round 5
// B=4, N=16384, DIM=256, H=8, D=64, G=32, inner=512. f32 I/O.
// r5 change: k5_attn rebuilt — r4 counters showed 106 us, VALUBusy 0.4%,
// 1.78M LDS bank conflicts: per-lane serial global W-loads (no TLP at 32
// blocks) + 32-way conflicts on kl[gk][d]. Now: W staged to LDS once,
// all LDS padded to ld=65 (conflict-free), k4b reduce fused in.
//   kgemm<0,32> : fxT[c][n] bf16 = (x @ Wfx + bfx)^T
//   kgemm<1,16> : softmax epilogue -> swb[n][256] + swT[bh*32+g][n] bf16
//   k4          : token_part = swT @ fx (MFMA split-K) + norm_part
//   k5          : fused reduce + norm + tiny attention -> osl f32
//   kZ          : ZT[b][c][hg] bf16 = (os_bh @ Wout_h)^T
//   kgemm<2,16> : out = swb @ ZT_b^T + bout -> d_out f32

typedef unsigned short u16;
typedef __attribute__((ext_vector_type(8))) unsigned short ushort8v;
typedef __attribute__((ext_vector_type(4))) unsigned short ushort4v;
typedef __attribute__((ext_vector_type(8))) short short8v;
typedef __attribute__((ext_vector_type(4))) float f32x4;

constexpr int Nc = 16384;
constexpr int BNc = 65536;

__device__ inline float b2f(u16 v) {
    union { unsigned int u; float f; } t; t.u = ((unsigned int)v) << 16; return t.f;
}
__device__ inline u16 f2b(float f) {   // round-to-nearest-even
    union { float f; unsigned int u; } t; t.f = f;
    unsigned int u = t.u;
    return (u16)((u + 0x7fffu + ((u >> 16) & 1u)) >> 16);
}

// ---------------- prep: fold WxsT[h*32+g][k] = (Wx_h @ Wslice)^T, bxs ------
__global__ __launch_bounds__(256) void k0_fold(
    const float* __restrict__ Wx, const float* __restrict__ Wslice,
    const float* __restrict__ bx, const float* __restrict__ bslice,
    u16* __restrict__ WxsT, float* __restrict__ bxs)
{
    int blk = blockIdx.x, tid = threadIdx.x;
    int h = tid >> 5, g = tid & 31;
    if (blk < 256) {
        int k = blk;
        float acc = 0.f;
        for (int d = 0; d < 64; d++)
            acc += Wx[k * 512 + h * 64 + d] * Wslice[d * 32 + g];
        WxsT[tid * 256 + k] = f2b(acc);
    } else {
        float acc = 0.f;
        for (int d = 0; d < 64; d++)
            acc += bx[h * 64 + d] * Wslice[d * 32 + g];
        bxs[tid] = acc + bslice[g];
    }
}

// ---------------- prep: WfxT[n][k] bf16 ----------------
__global__ __launch_bounds__(256) void kprep_wfx(const float* __restrict__ Wfx,
                                                 u16* __restrict__ WfxT)
{
    int n = blockIdx.x, k = threadIdx.x;        // 512 blocks x 256
    WfxT[n * 256 + k] = f2b(Wfx[k * 512 + n]);
}

// ------- MFMA GEMM, single-pass: 64 rows x NT*16 cols per block, BK=32. ----
template <int MODE, int NT>
__global__ __launch_bounds__(256, 2) void kgemm(
    const void* __restrict__ Ap, const u16* __restrict__ Bt,
    const float* __restrict__ bias, const float* __restrict__ temp,
    void* __restrict__ O1, u16* __restrict__ O2)
{
    constexpr int Kd = 256;
    __shared__ u16 Asl[4][64][8];          // [k-chunk][m][j]
    __shared__ u16 Bsl[NT * 16][4][8];     // [n][k-chunk][j]
    int tid = threadIdx.x;
    int wave = tid >> 6, lane = tid & 63;
    int lm = lane & 15, quad = lane >> 4;
    int row0 = blockIdx.x * 64;
    int sm = tid >> 2, skb = tid & 3;
    const u16* BtB = Bt;
    if (MODE == 2) BtB += (size_t)(row0 >> 14) * 65536;
    f32x4 acc[NT] = {};

    for (int k0 = 0; k0 < Kd; k0 += 32) {
        if (MODE < 2) {
            const float* A32 = (const float*)Ap;
            const f32x4* src = (const f32x4*)(A32 + (size_t)(row0 + sm) * Kd + k0 + skb * 8);
            f32x4 v0 = src[0], v1 = src[1];
            ushort8v o;
#pragma unroll
            for (int j = 0; j < 4; j++) { o[j] = f2b(v0[j]); o[4 + j] = f2b(v1[j]); }
            *(ushort8v*)&Asl[skb][sm][0] = o;
        } else {
            const u16* A16 = (const u16*)Ap;
            *(ushort8v*)&Asl[skb][sm][0] =
                *(const ushort8v*)(A16 + (size_t)(row0 + sm) * Kd + k0 + skb * 8);
        }
#pragma unroll
        for (int i = 0; i < NT / 4; i++) {
            int e = i * 256 + tid;
            int sn = e >> 2, sk = e & 3;
            *(ushort8v*)&Bsl[sn][sk][0] =
                *(const ushort8v*)(BtB + (size_t)sn * Kd + k0 + sk * 8);
        }
        __syncthreads();
        short8v af = *(short8v*)&Asl[quad][wave * 16 + lm][0];
#pragma unroll
        for (int nt = 0; nt < NT; nt++) {
            short8v bf = *(short8v*)&Bsl[nt * 16 + lm][quad][0];
            acc[nt] = __builtin_amdgcn_mfma_f32_16x16x32_bf16(af, bf, acc[nt], 0, 0, 0);
        }
        __syncthreads();
    }

    if (MODE == 0) {
        u16* fxT = (u16*)O1;
        int nbase = row0 + wave * 16 + quad * 4;
#pragma unroll
        for (int nt = 0; nt < NT; nt++) {
            int c = nt * 16 + lm;
            float bv = bias[c];
            ushort4v o;
#pragma unroll
            for (int r = 0; r < 4; r++) o[r] = f2b(acc[nt][r] + bv);
            *(ushort4v*)(fxT + (size_t)c * 65536 + nbase) = o;
        }
    } else if (MODE == 1) {
        int b = row0 >> 14;
        int nlbase = (row0 & 16383) + wave * 16 + quad * 4;
        u16* swb = (u16*)O1;
#pragma unroll
        for (int h = 0; h < 8; h++) {
            float it = 1.0f / temp[h];
            float bv0 = bias[h * 32 + lm];
            float bv1 = bias[h * 32 + 16 + lm];
            ushort4v p0, p1;
#pragma unroll
            for (int r = 0; r < 4; r++) {
                float v0 = (acc[2 * h][r] + bv0) * it;       // g = lm
                float v1 = (acc[2 * h + 1][r] + bv1) * it;   // g = 16+lm
                float m = fmaxf(v0, v1);
                m = fmaxf(m, __shfl_xor(m, 1));
                m = fmaxf(m, __shfl_xor(m, 2));
                m = fmaxf(m, __shfl_xor(m, 4));
                m = fmaxf(m, __shfl_xor(m, 8));
                float e0 = __expf(v0 - m), e1 = __expf(v1 - m);
                float s = e0 + e1;
                s += __shfl_xor(s, 1);
                s += __shfl_xor(s, 2);
                s += __shfl_xor(s, 4);
                s += __shfl_xor(s, 8);
                float rs = 1.0f / s;
                float w0 = e0 * rs, w1 = e1 * rs;
                int row = row0 + wave * 16 + quad * 4 + r;
                swb[(size_t)row * 256 + h * 32 + lm] = f2b(w0);
                swb[(size_t)row * 256 + h * 32 + 16 + lm] = f2b(w1);
                p0[r] = f2b(w0); p1[r] = f2b(w1);
            }
            size_t gbase = (size_t)((b * 8 + h) * 32);
            *(ushort4v*)(O2 + (gbase + lm) * 16384 + nlbase) = p0;
            *(ushort4v*)(O2 + (gbase + 16 + lm) * 16384 + nlbase) = p1;
        }
    } else {
        float* out = (float*)O1;
#pragma unroll
        for (int nt = 0; nt < NT; nt++) {
            int c = nt * 16 + lm;
            float bv = bias[c];
#pragma unroll
            for (int r = 0; r < 4; r++)
                out[(size_t)(row0 + wave * 16 + quad * 4 + r) * 256 + c] = acc[nt][r] + bv;
        }
    }
}

// ---------------- k4: token pooling via MFMA, split-K ----------------
__global__ __launch_bounds__(256) void k4_token_mfma(
    const u16* __restrict__ swT, const u16* __restrict__ fxT,
    float* __restrict__ token_part, float* __restrict__ norm_part)
{
    int bh = blockIdx.x, ky = blockIdx.y;
    int b = bh >> 3, h = bh & 7;
    int tid = threadIdx.x, wave = tid >> 6, lane = tid & 63;
    int lm = lane & 15, quad = lane >> 4;
    int mt = wave & 1, dp = wave >> 1;
    const u16* Ar = swT + ((size_t)(bh * 32 + mt * 16 + lm)) * 16384 + ky * 512 + quad * 8;
    const u16* Br0 = fxT + ((size_t)(h * 64 + dp * 32 + lm)) * 65536
                     + (size_t)b * 16384 + ky * 512 + quad * 8;
    const u16* Br1 = Br0 + (size_t)16 * 65536;
    f32x4 acc0 = {}, acc1 = {};
    float nacc = 0.f;
#pragma unroll
    for (int kk = 0; kk < 16; kk++) {
        short8v af = *(const short8v*)(Ar + kk * 32);
        short8v b0 = *(const short8v*)(Br0 + kk * 32);
        short8v b1 = *(const short8v*)(Br1 + kk * 32);
        acc0 = __builtin_amdgcn_mfma_f32_16x16x32_bf16(af, b0, acc0, 0, 0, 0);
        acc1 = __builtin_amdgcn_mfma_f32_16x16x32_bf16(af, b1, acc1, 0, 0, 0);
        if (dp == 0) {
            ushort8v au = (ushort8v&)af;
#pragma unroll
            for (int j = 0; j < 8; j++) nacc += b2f(au[j]);
        }
    }
    float* tp = token_part + ((size_t)(ky * 32 + bh)) * 2048;
#pragma unroll
    for (int r = 0; r < 4; r++) {
        int g = mt * 16 + quad * 4 + r;
        tp[g * 64 + dp * 32 + lm] = acc0[r];
        tp[g * 64 + dp * 32 + 16 + lm] = acc1[r];
    }
    if (dp == 0) {
        nacc += __shfl_xor(nacc, 16);
        nacc += __shfl_xor(nacc, 32);
        if (lane < 16)
            norm_part[(ky * 32 + bh) * 32 + mt * 16 + lm] = nacc;
    }
}

// ------- k5: fused (reduce partials -> norm -> tiny attention) per bh ------
// LDS padded to ld=65 -> conflict-free; Wq/Wk/Wv staged to LDS once.
__global__ __launch_bounds__(256) void k5_attn(
    const float* __restrict__ tp, const float* __restrict__ np,
    const float* __restrict__ Wq, const float* __restrict__ Wk, const float* __restrict__ Wv,
    float* __restrict__ out_slice)
{
    __shared__ float W[3][64][65];     // 50 KB
    __shared__ float tl[32][65];       // 8.3 KB
    __shared__ float ql[32][65], kl[32][65], vl[32][65];   // 25 KB
    __shared__ float sl[32][33];       // 4.2 KB
    __shared__ float nsh[32];
    int bh = blockIdx.x, tid = threadIdx.x;

    // stage Wq/Wk/Wv (coalesced float4)
    {
        const float* srcs[3] = { Wq, Wk, Wv };
#pragma unroll
        for (int m = 0; m < 3; m++) {
            const f32x4* src = (const f32x4*)srcs[m];
#pragma unroll
            for (int i = 0; i < 4; i++) {
                int e4 = i * 256 + tid;               // 1024 float4 = 4096 f
                f32x4 v = src[e4];
                int row = e4 >> 4, col = (e4 & 15) * 4;
#pragma unroll
                for (int j = 0; j < 4; j++) W[m][row][col + j] = v[j];
            }
        }
    }
    // norm reduce
    if (tid < 32) {
        float ns = 0.f;
        for (int ch = 0; ch < 32; ch++) ns += np[(ch * 32 + bh) * 32 + tid];
        nsh[tid] = ns + 1e-5f;
    }
    // token reduce (raw sums)
#pragma unroll
    for (int j = 0; j < 8; j++) {
        int e = j * 256 + tid;                        // 2048 elements
        float ts = 0.f;
        for (int ch = 0; ch < 32; ch++)
            ts += tp[((size_t)(ch * 32 + bh)) * 2048 + e];
        tl[e >> 6][e & 63] = ts;
    }
    __syncthreads();
    // divide by norm
#pragma unroll
    for (int j = 0; j < 8; j++) {
        int e = j * 256 + tid;
        tl[e >> 6][e & 63] /= nsh[e >> 6];
    }
    __syncthreads();
    // QKV projection (all LDS)
#pragma unroll
    for (int j = 0; j < 8; j++) {
        int idx = j * 256 + tid;
        int g = idx >> 6, d = idx & 63;
        float aq = 0.f, ak = 0.f, av = 0.f;
        for (int e = 0; e < 64; e++) {
            float t = tl[g][e];
            aq += t * W[0][e][d];
            ak += t * W[1][e][d];
            av += t * W[2][e][d];
        }
        ql[g][d] = aq; kl[g][d] = ak; vl[g][d] = av;
    }
    __syncthreads();
    // scores
#pragma unroll
    for (int j = 0; j < 4; j++) {
        int idx = j * 256 + tid;
        int gq = idx >> 5, gk = idx & 31;
        float s = 0.f;
        for (int d = 0; d < 64; d++) s += ql[gq][d] * kl[gk][d];
        sl[gq][gk] = s * 0.125f;   // 1/sqrt(64)
    }
    __syncthreads();
    if (tid < 32) {
        float m = -1e30f;
        for (int k2 = 0; k2 < 32; k2++) m = fmaxf(m, sl[tid][k2]);
        float s = 0.f;
        for (int k2 = 0; k2 < 32; k2++) { float e = __expf(sl[tid][k2] - m); sl[tid][k2] = e; s += e; }
        float r = 1.0f / s;
        for (int k2 = 0; k2 < 32; k2++) sl[tid][k2] *= r;
    }
    __syncthreads();
    // attn @ V
#pragma unroll
    for (int j = 0; j < 8; j++) {
        int idx = j * 256 + tid;
        int g = idx >> 6, d = idx & 63;
        float a = 0.f;
        for (int k2 = 0; k2 < 32; k2++) a += sl[g][k2] * vl[k2][d];
        out_slice[(size_t)bh * 2048 + idx] = a;
    }
}

// ---------------- kZ: ZT[b][c][hg] = (os_bh @ Wout_h)^T, bf16 -------------
__global__ __launch_bounds__(256) void kZ(
    const float* __restrict__ os, const float* __restrict__ Wout,
    u16* __restrict__ ZT)
{
    int b = blockIdx.x, cb = blockIdx.y;   // grid (4, 16)
    int t = threadIdx.x;
    int c = cb * 16 + (t & 15), kq = t >> 4;
    for (int k = kq * 16; k < kq * 16 + 16; k++) {
        int h = k >> 5, g = k & 31;
        const float* osr = os + ((size_t)(b * 8 + h)) * 2048 + g * 64;
        float acc = 0.f;
        for (int d = 0; d < 64; d++)
            acc += osr[d] * Wout[(h * 64 + d) * 256 + c];
        ZT[(size_t)b * 65536 + c * 256 + k] = f2b(acc);
    }
}

// ---------------- launcher ----------------
extern "C" void kernel_launch(void* const* d_in, const int* in_sizes, int n_in,
                              void* d_out, int out_size, void* d_ws, size_t ws_size,
                              hipStream_t stream)
{
    const float* x      = (const float*)d_in[0];
    const float* Wfx    = (const float*)d_in[1];
    const float* bfx    = (const float*)d_in[2];
    const float* Wx     = (const float*)d_in[3];
    const float* bx     = (const float*)d_in[4];
    const float* Wslice = (const float*)d_in[5];
    const float* bslice = (const float*)d_in[6];
    const float* temp   = (const float*)d_in[7];
    const float* Wq     = (const float*)d_in[8];
    const float* Wk     = (const float*)d_in[9];
    const float* Wv     = (const float*)d_in[10];
    const float* Wout   = (const float*)d_in[11];
    const float* bout   = (const float*)d_in[12];

    char* ws = (char*)d_ws;
    size_t off = 0;
    auto alloc = [&](size_t bytes) {
        void* p = ws + off;
        off = (off + bytes + 255) & ~(size_t)255;
        return p;
    };
    u16*   fxT   = (u16*)  alloc((size_t)512 * BNc * 2);   // 64 MiB
    u16*   swb   = (u16*)  alloc((size_t)BNc * 256 * 2);   // 32 MiB
    u16*   swT   = (u16*)  alloc((size_t)1024 * Nc * 2);   // 32 MiB
    float* tp    = (float*)alloc((size_t)1024 * 2048 * 4); // 8 MiB
    float* np    = (float*)alloc(32768 * 4);               // 128 KiB
    float* osl   = (float*)alloc(65536 * 4);               // 256 KiB
    u16*   ZT    = (u16*)  alloc(4 * 65536 * 2);           // 512 KiB
    u16*   WfxT  = (u16*)  alloc(512 * 256 * 2);
    u16*   WxsT  = (u16*)  alloc(256 * 256 * 2);
    float* bxs   = (float*)alloc(256 * 4);

    k0_fold<<<257, 256, 0, stream>>>(Wx, Wslice, bx, bslice, WxsT, bxs);
    kprep_wfx<<<512, 256, 0, stream>>>(Wfx, WfxT);

    // fxT = (x @ Wfx + bfx)^T  bf16 [512][65536]  — single pass over x
    kgemm<0, 32><<<1024, 256, 0, stream>>>(x, WfxT, bfx, nullptr, fxT, nullptr);

    // softmax(x @ Wxs + bxs) -> swb [n][256] + swT [bh*32+g][16384]
    kgemm<1, 16><<<1024, 256, 0, stream>>>(x, WxsT, bxs, temp, swb, swT);

    k4_token_mfma<<<dim3(32, 32), 256, 0, stream>>>(swT, fxT, tp, np);
    k5_attn<<<32, 256, 0, stream>>>(tp, np, Wq, Wk, Wv, osl);
    kZ<<<dim3(4, 16), 256, 0, stream>>>(osl, Wout, ZT);

    // out = swb @ ZT_b^T + bout -> f32 d_out
    kgemm<2, 16><<<1024, 256, 0, stream>>>(swb, ZT, bout, nullptr, d_out, nullptr);
}